// Round 2
// baseline (67.799 us; speedup 1.0000x reference)
//
#include <hip/hip_runtime.h>

// Problem constants (fixed by the reference)
#define BB   32
#define NN   256
#define DD   3
#define HH   64
#define EPS  1e-6f

// f(d) / f'(d) lookup table
#define TABN   2048
#define DMAX   16.0f
#define DX     (DMAX / (float)(TABN - 1))
#define INV_DX ((float)(TABN - 1) / DMAX)

#define ROWS (BB * NN)  // 8192

// ws layout: [tab: TABN*float2][v: ROWS*3 f32][P: ROWS f32][cnt: BB u32]
#define WS_V_OFF   (TABN * 8)
#define WS_P_OFF   (WS_V_OFF + ROWS * 3 * 4)
#define WS_CNT_OFF (WS_P_OFF + ROWS * 4)

// fast tanh: 1 - 2/(e^{2x}+1). Saturates correctly at +-1; err ~1e-6.
__device__ __forceinline__ float ftanh(float x) {
  float e = __expf(2.0f * x);
  return 1.0f - 2.0f / (e + 1.0f);
}

// ---------------------------------------------------------------------------
// Kernel 1: exact MLP (value + analytic d-derivative) at table nodes.
// 16 threads per node: 8 m-subgroups x 2 h-halves (serial h-loop is 32 iters).
// Also zeroes the per-batch arrival counters for kernel 2.
// ---------------------------------------------------------------------------
__global__ __launch_bounds__(256) void build_table_kernel(
    const float* __restrict__ W1, const float* __restrict__ b1,
    const float* __restrict__ W2, const float* __restrict__ b2,
    const float* __restrict__ W3, const float* __restrict__ b3,
    const float* __restrict__ t,  float2* __restrict__ tab,
    unsigned* __restrict__ cnt) {
  __shared__ float sW2[HH * HH];
  int tid = threadIdx.x;
  const float4* w24 = (const float4*)W2;
  for (int i = tid; i < HH * HH / 4; i += 256) ((float4*)sW2)[i] = w24[i];
  if (blockIdx.x == 0 && tid < BB) cnt[tid] = 0u;
  __syncthreads();

  int gid  = blockIdx.x * 256 + tid;
  int node = gid >> 4;
  int sub  = gid & 15;
  int msub = sub & 7;
  int hh   = sub >> 3;
  int m0   = msub * 8;

  float d  = (float)node * DX;
  float tt = t[0];

  float u[8], w[8];
#pragma unroll
  for (int m = 0; m < 8; ++m) { u[m] = hh ? 0.f : b2[m0 + m]; w[m] = 0.f; }

  int hbase = hh * 32;
  for (int hi = 0; hi < 32; ++hi) {
    int   h  = hbase + hi;
    float a  = W1[h];                                    // W1[0,h] (d coeff)
    float z  = fmaf(a, d, fmaf(W1[HH + h], tt, b1[h]));  // W1[1,h]*t + b1
    float th = ftanh(z);
    float g  = (1.f - th * th) * a;                      // dh1/dd
#pragma unroll
    for (int m = 0; m < 8; ++m) {
      float wv = sW2[h * HH + m0 + m];
      u[m] = fmaf(th, wv, u[m]);
      w[m] = fmaf(g,  wv, w[m]);
    }
  }
  // merge the two h-halves (lanes differing in bit 3)
#pragma unroll
  for (int m = 0; m < 8; ++m) {
    u[m] += __shfl_xor(u[m], 8, 64);
    w[m] += __shfl_xor(w[m], 8, 64);
  }

  float f = 0.f, fp = 0.f;
#pragma unroll
  for (int m = 0; m < 8; ++m) {
    float th = ftanh(u[m]);
    float w3 = W3[m0 + m];
    f  = fmaf(th, w3, f);
    fp = fmaf((1.f - th * th) * w[m], w3, fp);
  }
  // reduce across the 8 m-subgroups (both halves hold identical values)
#pragma unroll
  for (int off = 1; off < 8; off <<= 1) {
    f  += __shfl_xor(f,  off, 64);
    fp += __shfl_xor(fp, off, 64);
  }
  if (sub == 0) tab[node] = make_float2(f + b3[0], fp);
}

// ---------------------------------------------------------------------------
// Kernel 2: fused pair-sum + per-batch finalize.
// 512 blocks x 1024 threads; block (b, ig) handles rows ig*16..ig*16+15 of
// batch b (one row per wave). Last-arriving block per batch (device-scope
// atomic counter) performs the mean-subtract + trace reduction.
// ---------------------------------------------------------------------------
__global__ __launch_bounds__(1024) void pair_fused_kernel(
    const float* __restrict__ x, const float2* __restrict__ tab,
    float* __restrict__ v, float* __restrict__ P,
    unsigned* __restrict__ cnt, float* __restrict__ out) {
  __shared__ float sx[NN * DD];
  __shared__ float red[4][4];
  __shared__ int   sLast;

  int tid = threadIdx.x;
  int bid = blockIdx.x;
  int b   = bid >> 4;   // 16 blocks per batch
  int ig  = bid & 15;

  const float4* xb4 = (const float4*)(x + b * (NN * DD));
  if (tid < NN * DD / 4) ((float4*)sx)[tid] = xb4[tid];
  __syncthreads();

  int w    = tid >> 6;        // wave 0..15
  int lane = tid & 63;
  int i    = ig * 16 + w;     // row within batch
  int row  = b * NN + i;

  float xi0 = sx[i * 3 + 0], xi1 = sx[i * 3 + 1], xi2 = sx[i * 3 + 2];
  float vx = 0.f, vy = 0.f, vz = 0.f, tr = 0.f;

#pragma unroll
  for (int q = 0; q < 4; ++q) {
    int j = lane + q * 64;
    if (j == i) continue;
    float r0  = xi0 - sx[j * 3 + 0];
    float r1  = xi1 - sx[j * 3 + 1];
    float r2  = xi2 - sx[j * 3 + 2];
    float dot = fmaf(r0, r0, fmaf(r1, r1, r2 * r2));
    float d   = sqrtf(dot + EPS);

    float s = d * INV_DX;
    int   k = (int)s;
    if (k > TABN - 2) k = TABN - 2;
    float uu = s - (float)k;

    float2 t0 = tab[k];
    float2 t1 = tab[k + 1];
    float  m0 = t0.y * DX, m1 = t1.y * DX;   // derivatives in u-space
    float  u2 = uu * uu, u3 = u2 * uu;

    float h00 = 2.f * u3 - 3.f * u2 + 1.f;
    float h10 = u3 - 2.f * u2 + uu;
    float h11 = u3 - u2;
    float f   = h00 * (t0.x - t1.x) + t1.x + h10 * m0 + h11 * m1;

    float dh00 = 6.f * u2 - 6.f * uu;
    float dh10 = 3.f * u2 - 4.f * uu + 1.f;
    float dh11 = 3.f * u2 - 2.f * uu;
    float fp   = (dh00 * (t0.x - t1.x) + dh10 * m0 + dh11 * m1) * INV_DX;

    vx = fmaf(r0, f, vx);
    vy = fmaf(r1, f, vy);
    vz = fmaf(r2, f, vz);
    tr += fmaf(dot / d, fp, 3.f * f);
  }

#pragma unroll
  for (int off = 1; off < 64; off <<= 1) {
    vx += __shfl_xor(vx, off, 64);
    vy += __shfl_xor(vy, off, 64);
    vz += __shfl_xor(vz, off, 64);
    tr += __shfl_xor(tr, off, 64);
  }
  if (lane == 0) {
    const float inv = 1.f / (float)(NN - 1);
    v[row * 3 + 0] = vx * inv;
    v[row * 3 + 1] = vy * inv;
    v[row * 3 + 2] = vz * inv;
    P[row] = tr;
  }

  // --- arrival: each wave drains vmem at the barrier; thread 0 releases ---
  __syncthreads();
  if (tid == 0) {
    __threadfence();
    unsigned old = __hip_atomic_fetch_add(&cnt[b], 1u, __ATOMIC_ACQ_REL,
                                          __HIP_MEMORY_SCOPE_AGENT);
    sLast = (old == 15u);
  }
  __syncthreads();

  if (sLast) {
    __threadfence();  // acquire: invalidate caches before reading others' v/P
    float v0 = 0.f, v1 = 0.f, v2 = 0.f, p = 0.f;
    if (tid < NN) {
      int r2 = b * NN + tid;
      v0 = v[r2 * 3 + 0];
      v1 = v[r2 * 3 + 1];
      v2 = v[r2 * 3 + 2];
      p  = P[r2];
      float s0 = v0, s1 = v1, s2 = v2, sp = p;
#pragma unroll
      for (int off = 1; off < 64; off <<= 1) {
        s0 += __shfl_xor(s0, off, 64);
        s1 += __shfl_xor(s1, off, 64);
        s2 += __shfl_xor(s2, off, 64);
        sp += __shfl_xor(sp, off, 64);
      }
      if ((tid & 63) == 0) {
        int ww = tid >> 6;
        red[0][ww] = s0; red[1][ww] = s1; red[2][ww] = s2; red[3][ww] = sp;
      }
    }
    __syncthreads();
    if (tid < NN) {
      float t0 = (red[0][0] + red[0][1]) + (red[0][2] + red[0][3]);
      float t1 = (red[1][0] + red[1][1]) + (red[1][2] + red[1][3]);
      float t2 = (red[2][0] + red[2][1]) + (red[2][2] + red[2][3]);
      const float invN = 1.f / (float)NN;
      out[b * (NN * DD) + tid * 3 + 0] = v0 - t0 * invN;
      out[b * (NN * DD) + tid * 3 + 1] = v1 - t1 * invN;
      out[b * (NN * DD) + tid * 3 + 2] = v2 - t2 * invN;
      if (tid == 0) {
        float tp = (red[3][0] + red[3][1]) + (red[3][2] + red[3][3]);
        out[BB * NN * DD + b] = tp * invN;
      }
    }
  }
}

// ---------------------------------------------------------------------------
extern "C" void kernel_launch(void* const* d_in, const int* in_sizes, int n_in,
                              void* d_out, int out_size, void* d_ws, size_t ws_size,
                              hipStream_t stream) {
  const float* t  = (const float*)d_in[0];
  const float* x  = (const float*)d_in[1];
  const float* W1 = (const float*)d_in[2];
  const float* b1 = (const float*)d_in[3];
  const float* W2 = (const float*)d_in[4];
  const float* b2 = (const float*)d_in[5];
  const float* W3 = (const float*)d_in[6];
  const float* b3 = (const float*)d_in[7];

  char*     ws  = (char*)d_ws;
  float2*   tab = (float2*)ws;
  float*    v   = (float*)(ws + WS_V_OFF);
  float*    P   = (float*)(ws + WS_P_OFF);
  unsigned* cnt = (unsigned*)(ws + WS_CNT_OFF);
  float*    out = (float*)d_out;

  hipLaunchKernelGGL(build_table_kernel, dim3(TABN * 16 / 256), dim3(256), 0,
                     stream, W1, b1, W2, b2, W3, b3, t, tab, cnt);
  hipLaunchKernelGGL(pair_fused_kernel, dim3(ROWS / 16), dim3(1024), 0, stream,
                     x, tab, v, P, cnt, out);
}

// Round 3
// 20.432 us; speedup vs baseline: 3.3183x; 3.3183x over previous
//
#include <hip/hip_runtime.h>

// Problem constants (fixed by the reference)
#define BB   32
#define NN   256
#define DD   3
#define HH   64
#define EPS  1e-6f

// f(d) / f'(d) lookup table
#define TABN   2048
#define DMAX   16.0f
#define DX     (DMAX / (float)(TABN - 1))
#define INV_DX ((float)(TABN - 1) / DMAX)

#define ROWS (BB * NN)          // 8192
#define TR_OFF (BB * NN * DD)   // trace slots at out[24576..24607]

// fast tanh: 1 - 2/(e^{2x}+1). Saturates correctly at +-1; err ~1e-6.
__device__ __forceinline__ float ftanh(float x) {
  float e = __expf(2.0f * x);
  return 1.0f - 2.0f / (e + 1.0f);
}

// ---------------------------------------------------------------------------
// Kernel 1: exact MLP (value + analytic d-derivative) at table nodes.
// 16 threads per node: 8 m-subgroups x 2 h-halves. Also zeroes the per-batch
// trace accumulators in d_out (kernel 2 atomically adds into them).
// ---------------------------------------------------------------------------
__global__ __launch_bounds__(256) void build_table_kernel(
    const float* __restrict__ W1, const float* __restrict__ b1,
    const float* __restrict__ W2, const float* __restrict__ b2,
    const float* __restrict__ W3, const float* __restrict__ b3,
    const float* __restrict__ t,  float2* __restrict__ tab,
    float* __restrict__ out) {
  __shared__ float sW2[HH * HH];
  int tid = threadIdx.x;
  const float4* w24 = (const float4*)W2;
  for (int i = tid; i < HH * HH / 4; i += 256) ((float4*)sW2)[i] = w24[i];
  if (blockIdx.x == 0 && tid < BB) out[TR_OFF + tid] = 0.0f;
  __syncthreads();

  int gid  = blockIdx.x * 256 + tid;
  int node = gid >> 4;
  int sub  = gid & 15;
  int msub = sub & 7;
  int hh   = sub >> 3;
  int m0   = msub * 8;

  float d  = (float)node * DX;
  float tt = t[0];

  float u[8], w[8];
#pragma unroll
  for (int m = 0; m < 8; ++m) { u[m] = hh ? 0.f : b2[m0 + m]; w[m] = 0.f; }

  int hbase = hh * 32;
  for (int hi = 0; hi < 32; ++hi) {
    int   h  = hbase + hi;
    float a  = W1[h];                                    // W1[0,h] (d coeff)
    float z  = fmaf(a, d, fmaf(W1[HH + h], tt, b1[h]));  // W1[1,h]*t + b1
    float th = ftanh(z);
    float g  = (1.f - th * th) * a;                      // dh1/dd
#pragma unroll
    for (int m = 0; m < 8; ++m) {
      float wv = sW2[h * HH + m0 + m];
      u[m] = fmaf(th, wv, u[m]);
      w[m] = fmaf(g,  wv, w[m]);
    }
  }
  // merge the two h-halves (lanes differing in bit 3)
#pragma unroll
  for (int m = 0; m < 8; ++m) {
    u[m] += __shfl_xor(u[m], 8, 64);
    w[m] += __shfl_xor(w[m], 8, 64);
  }

  float f = 0.f, fp = 0.f;
#pragma unroll
  for (int m = 0; m < 8; ++m) {
    float th = ftanh(u[m]);
    float w3 = W3[m0 + m];
    f  = fmaf(th, w3, f);
    fp = fmaf((1.f - th * th) * w[m], w3, fp);
  }
  // reduce across the 8 m-subgroups (both halves hold identical values)
#pragma unroll
  for (int off = 1; off < 8; off <<= 1) {
    f  += __shfl_xor(f,  off, 64);
    fp += __shfl_xor(fp, off, 64);
  }
  if (sub == 0) tab[node] = make_float2(f + b3[0], fp);
}

// ---------------------------------------------------------------------------
// Kernel 2: pair sums. Block (b, ig) = 16 waves, one row per wave.
// y = v written directly (sum_i v == 0 analytically, so the reference's
// mean-subtraction is pure fp noise ~1e-7 -- skipped). Trace partial:
// one atomicAdd per block into out[TR_OFF + b] (zeroed by kernel 1).
// No fences, no cross-block ordering.
// ---------------------------------------------------------------------------
__global__ __launch_bounds__(1024) void pair_kernel(
    const float* __restrict__ x, const float2* __restrict__ tab,
    float* __restrict__ out) {
  __shared__ float sx[NN * DD];
  __shared__ float str[16];

  int tid = threadIdx.x;
  int bid = blockIdx.x;
  int b   = bid >> 4;   // 16 blocks per batch
  int ig  = bid & 15;

  const float4* xb4 = (const float4*)(x + b * (NN * DD));
  if (tid < NN * DD / 4) ((float4*)sx)[tid] = xb4[tid];
  __syncthreads();

  int w    = tid >> 6;        // wave 0..15
  int lane = tid & 63;
  int i    = ig * 16 + w;     // row within batch

  float xi0 = sx[i * 3 + 0], xi1 = sx[i * 3 + 1], xi2 = sx[i * 3 + 2];
  float vx = 0.f, vy = 0.f, vz = 0.f, tr = 0.f;

#pragma unroll
  for (int q = 0; q < 4; ++q) {
    int j = lane + q * 64;
    if (j == i) continue;
    float r0  = xi0 - sx[j * 3 + 0];
    float r1  = xi1 - sx[j * 3 + 1];
    float r2  = xi2 - sx[j * 3 + 2];
    float dot = fmaf(r0, r0, fmaf(r1, r1, r2 * r2));
    float d   = sqrtf(dot + EPS);

    float s = d * INV_DX;
    int   k = (int)s;
    if (k > TABN - 2) k = TABN - 2;
    float uu = s - (float)k;

    float2 t0 = tab[k];
    float2 t1 = tab[k + 1];
    float  m0 = t0.y * DX, m1 = t1.y * DX;   // derivatives in u-space
    float  u2 = uu * uu, u3 = u2 * uu;

    float h00 = 2.f * u3 - 3.f * u2 + 1.f;
    float h10 = u3 - 2.f * u2 + uu;
    float h11 = u3 - u2;
    float f   = h00 * (t0.x - t1.x) + t1.x + h10 * m0 + h11 * m1;

    float dh00 = 6.f * u2 - 6.f * uu;
    float dh10 = 3.f * u2 - 4.f * uu + 1.f;
    float dh11 = 3.f * u2 - 2.f * uu;
    float fp   = (dh00 * (t0.x - t1.x) + dh10 * m0 + dh11 * m1) * INV_DX;

    vx = fmaf(r0, f, vx);
    vy = fmaf(r1, f, vy);
    vz = fmaf(r2, f, vz);
    tr += fmaf(dot / d, fp, 3.f * f);
  }

#pragma unroll
  for (int off = 1; off < 64; off <<= 1) {
    vx += __shfl_xor(vx, off, 64);
    vy += __shfl_xor(vy, off, 64);
    vz += __shfl_xor(vz, off, 64);
    tr += __shfl_xor(tr, off, 64);
  }
  if (lane == 0) {
    const float inv = 1.f / (float)(NN - 1);
    int row = b * NN + i;
    out[row * 3 + 0] = vx * inv;   // y = v (mean over i is exactly 0)
    out[row * 3 + 1] = vy * inv;
    out[row * 3 + 2] = vz * inv;
    str[w] = tr;
  }
  __syncthreads();

  if (tid == 0) {
    float s = 0.f;
#pragma unroll
    for (int k = 0; k < 16; ++k) s += str[k];
    atomicAdd(&out[TR_OFF + b], s * (1.f / (float)NN));
  }
}

// ---------------------------------------------------------------------------
extern "C" void kernel_launch(void* const* d_in, const int* in_sizes, int n_in,
                              void* d_out, int out_size, void* d_ws, size_t ws_size,
                              hipStream_t stream) {
  const float* t  = (const float*)d_in[0];
  const float* x  = (const float*)d_in[1];
  const float* W1 = (const float*)d_in[2];
  const float* b1 = (const float*)d_in[3];
  const float* W2 = (const float*)d_in[4];
  const float* b2 = (const float*)d_in[5];
  const float* W3 = (const float*)d_in[6];
  const float* b3 = (const float*)d_in[7];

  float2* tab = (float2*)d_ws;
  float*  out = (float*)d_out;

  hipLaunchKernelGGL(build_table_kernel, dim3(TABN * 16 / 256), dim3(256), 0,
                     stream, W1, b1, W2, b2, W3, b3, t, tab, out);
  hipLaunchKernelGGL(pair_kernel, dim3(ROWS / 16), dim3(1024), 0, stream,
                     x, tab, out);
}